// Round 2
// baseline (425.764 us; speedup 1.0000x reference)
//
#include <hip/hip_runtime.h>
#include <stdint.h>

#define NUM_HEADS 16
#define HIDDEN    2048
#define HEAD_SIZE 128
#define TOTAL     4096
#define SEQ       1024
#define QKV_N     (3*HIDDEN)   // 6144

typedef __bf16 bf16x8 __attribute__((ext_vector_type(8)));
typedef float  f32x4  __attribute__((ext_vector_type(4)));

__device__ __forceinline__ unsigned short f2bf(float f) {
  unsigned u = __float_as_uint(f);
  u += 0x7FFFu + ((u >> 16) & 1u);          // RNE
  return (unsigned short)(u >> 16);
}
__device__ __forceinline__ float bf2f(unsigned short h) {
  return __uint_as_float(((unsigned)h) << 16);
}
// async global->LDS, 16B per lane. LDS dest must be wave-uniform base + lane*16.
__device__ __forceinline__ void cp16(void* lds, const void* g) {
  __builtin_amdgcn_global_load_lds(
      (const __attribute__((address_space(1))) void*)g,
      (__attribute__((address_space(3))) void*)lds, 16, 0, 0);
}

// ---------------------------------------------------------------- fused convert (3 tensors)
__global__ __launch_bounds__(256) void f32_to_bf16_multi(
    const float* __restrict__ a, unsigned short* __restrict__ oa, int na,
    const float* __restrict__ b, unsigned short* __restrict__ ob, int nb,
    const float* __restrict__ c, unsigned short* __restrict__ oc, int nc)
{
  int i = (blockIdx.x * 256 + threadIdx.x) * 4;
  const float* src; unsigned short* dst;
  if (i < na)            { src = a; dst = oa; }
  else if (i < na + nb)  { i -= na; src = b; dst = ob; }
  else                   { i -= na + nb; if (i >= nc) return; src = c; dst = oc; }
  float4 v = *(const float4*)(src + i);
  unsigned p0 = (unsigned)f2bf(v.x) | ((unsigned)f2bf(v.y) << 16);
  unsigned p1 = (unsigned)f2bf(v.z) | ((unsigned)f2bf(v.w) << 16);
  uint2 pk; pk.x = p0; pk.y = p1;
  *(uint2*)(dst + i) = pk;
}

// ---------------------------------------------------------------- 8-phase helpers
#define SBAR()   __builtin_amdgcn_sched_barrier(0)
#define HBAR()   __builtin_amdgcn_s_barrier()
#define WVMC(n)  asm volatile("s_waitcnt vmcnt(" #n ")" ::: "memory")
// barrier, then COUNTED lgkm wait: the N newest ds_reads (issued this phase,
// feeding the NEXT phase) stay in flight; everything older is complete.
#define PH_PRE(n) do { SBAR(); HBAR(); \
    asm volatile("s_waitcnt lgkmcnt(" #n ")" ::: "memory"); SBAR(); } while (0)
#define PH_END()  do { SBAR(); HBAR(); } while (0)

__device__ __forceinline__ void stage2(char* lb, const char* sb, int o0, int o1,
                                       size_t gg0, size_t gg1) {
  cp16(lb + o0, sb + gg0);
  cp16(lb + o1, sb + gg1);
}

// LDS rows are 128B (64 bf16). Chunk swizzle: 16B-chunk c at row r holds global
// chunk c ^ (r&7) (involution; stage pre-swizzles the GLOBAL source, reads XOR).
template<int MH>
__device__ __forceinline__ void ldA4(bf16x8 (&d)[4][2], const unsigned short* ls,
                                     int base, int ch0) {
#pragma unroll
  for (int mi = 0; mi < 4; mi++) {
    d[mi][0] = *(const bf16x8*)((const char*)ls + base + (MH*4 + mi)*2048 + ch0);
    d[mi][1] = *(const bf16x8*)((const char*)ls + base + (MH*4 + mi)*2048 + (ch0 ^ 64));
  }
}
template<int NH>
__device__ __forceinline__ void ldB2(bf16x8 (&d)[2][2], const unsigned short* ls,
                                     int base, int ch0) {
#pragma unroll
  for (int ni = 0; ni < 2; ni++) {
    d[ni][0] = *(const bf16x8*)((const char*)ls + base + (NH*2 + ni)*2048 + ch0);
    d[ni][1] = *(const bf16x8*)((const char*)ls + base + (NH*2 + ni)*2048 + (ch0 ^ 64));
  }
}
template<int MH, int NH>
__device__ __forceinline__ void mfmaQ(f32x4 (&acc)[8][4], const bf16x8 (&AF)[4][2],
                                      const bf16x8 (&BF)[2][2]) {
  __builtin_amdgcn_s_setprio(1);
#pragma unroll
  for (int kk = 0; kk < 2; kk++)
#pragma unroll
    for (int mi = 0; mi < 4; mi++)
#pragma unroll
      for (int ni = 0; ni < 2; ni++)
        acc[MH*4 + mi][NH*2 + ni] = __builtin_amdgcn_mfma_f32_16x16x32_bf16(
            AF[mi][kk], BF[ni][kk], acc[MH*4 + mi][NH*2 + ni], 0, 0, 0);
  __builtin_amdgcn_s_setprio(0);
}

// ---------------------------------------------------------------- QKV GEMM, 256x256 8-phase
// 8 waves (2M x 4N), per-wave C = 128x64 (acc[8][4] -> AGPR). BK=64.
// LDS: 2 x (A 256x64 + B 256x64) bf16 = 128 KiB -> 1 block/CU.
// PIPELINED schedule: each phase ISSUES the next quadrant's ds_reads and
// CONSUMES the previous phase's (counted lgkmcnt) -- ds latency hides under
// the 16-MFMA cluster instead of serializing before it (R1 post-mortem).
// Quadrant MFMA order: (0,0)(1,0)(0,1)(1,1); reads: a1@p1, b1@p2, -, a0b0'@p4,
// a1'@p5, b1'@p6, -, a0b0''@p8. vmcnt ledger (2 loads/STG, in-flight tracked):
// enter p1 with 4; p3/p7: WVMC(2) == tile t+1/t+2 fully staged; barrier at p3/p7
// makes the fresh buffer visible BEFORE its reads issue at p4/p8 (cross-wave
// staging => reads of a fresh buffer only after an all-waves-vmcnt'd barrier).
__global__ __launch_bounds__(512, 2) void gemm_qkv_8ph(
    const unsigned short* __restrict__ A,   // [M=4096][K=2048] bf16
    const unsigned short* __restrict__ B,   // [N=6144][K=2048] bf16
    const float* __restrict__ bias,         // [N]
    const int* __restrict__ pos_ids,        // [TOTAL]
    unsigned short* __restrict__ Qb,
    unsigned short* __restrict__ Kb,
    unsigned short* __restrict__ Vt)
{
  __shared__ unsigned short lsA[2][256*64]; // 2 x 32 KB
  __shared__ unsigned short lsB[2][256*64]; // 2 x 32 KB

  const int tid  = threadIdx.x;
  const int w    = tid >> 6, lane = tid & 63;
  const int quad = lane >> 4, lm = lane & 15;
  const int wm   = w >> 2, wn = w & 3;

  // bijective XCD swizzle: 384 blocks, 48/XCD
  const int g  = ((int)blockIdx.x & 7) * 48 + ((int)blockIdx.x >> 3);
  const int my = g & 15, nx = g >> 4;
  const int mBase = my * 256, nBase = nx * 256;

  // staging constants: linear LDS dest, inverse-swizzled global source (rule 21)
  const int off0 = tid * 16;                 // i=0 byte offset in 16KB half-tile
  const int off1 = off0 + 8192;
  const int r0 = off0 >> 7, r1 = off1 >> 7;
  const size_t g0 = (size_t)r0 * (HIDDEN*2) + ((((off0 >> 4) & 7) ^ (r0 & 7)) << 4);
  const size_t g1 = (size_t)r1 * (HIDDEN*2) + ((((off1 >> 4) & 7) ^ (r1 & 7)) << 4);
  const char* Abase = (const char*)A + (size_t)mBase * HIDDEN * 2;
  const char* Bbase = (const char*)B + (size_t)nBase * HIDDEN * 2;

  // read-side constants: chunk(kk) = ((kk*4+quad) ^ (lm&7)), byte = row*128 + chunk*16
  const int ch0   = ((quad ^ (lm & 7)) << 4);
  const int aBase = (wm * 128 + lm) * 128;
  const int bBase = (wn * 64  + lm) * 128;

// h: 0=A rows 0-127, 1=A rows 128-255, 2=B rows 0-127, 3=B rows 128-255
#define STG(bi, h, t) stage2( \
    (((h) < 2) ? (char*)&lsA[bi][0] : (char*)&lsB[bi][0]) + (((h) & 1) * 16384), \
    (((h) < 2) ? Abase : Bbase) + (size_t)((h) & 1) * (128 * HIDDEN * 2) + (size_t)(t) * 128, \
    off0, off1, g0, g1)

  const f32x4 zero4 = {0.f, 0.f, 0.f, 0.f};
  f32x4 acc[8][4];
#pragma unroll
  for (int i = 0; i < 8; i++)
#pragma unroll
    for (int j = 0; j < 4; j++) acc[i][j] = zero4;

  bf16x8 a0[4][2], a1[4][2], b0[2][2], b1[2][2];

  // prologue: tile0 -> buf0 (8 loads), tile1 A halves -> buf1 (4 loads);
  // wait tile0 (vmcnt<=4), barrier (buf0 visible), then issue p1's operands.
  STG(0, 0, 0); STG(0, 1, 0); STG(0, 2, 0); STG(0, 3, 0);
  STG(1, 0, 1); STG(1, 1, 1);
  WVMC(4);
  SBAR(); HBAR();
  ldA4<0>(a0, &lsA[0][0], aBase, ch0);       // 12 ds_reads in flight
  ldB2<0>(b0, &lsB[0][0], bBase, ch0);

#pragma unroll 1
  for (int t = 0; t < 30; t += 2) {
    // ---- buf0: tile t
    ldA4<1>(a1, &lsA[0][0], aBase, ch0);     // p1 (+8 rd)
    STG(1, 2, t + 1);
    PH_PRE(8); mfmaQ<0,0>(acc, a0, b0); PH_END();

    ldB2<1>(b1, &lsB[0][0], bBase, ch0);     // p2 (+4 rd)
    STG(1, 3, t + 1);
    PH_PRE(4); mfmaQ<1,0>(acc, a1, b0); PH_END();

    STG(0, 0, t + 2);                        // p3
    WVMC(2);                                 // tile t+1 fully staged
    PH_PRE(0); mfmaQ<0,1>(acc, a0, b1); PH_END();

    ldA4<0>(a0, &lsA[1][0], aBase, ch0);     // p4 (+12 rd, buf1 now visible)
    ldB2<0>(b0, &lsB[1][0], bBase, ch0);
    STG(0, 1, t + 2);
    PH_PRE(12); mfmaQ<1,1>(acc, a1, b1); PH_END();

    // ---- buf1: tile t+1
    ldA4<1>(a1, &lsA[1][0], aBase, ch0);     // p5 (+8 rd)
    STG(0, 2, t + 2);
    PH_PRE(8); mfmaQ<0,0>(acc, a0, b0); PH_END();

    ldB2<1>(b1, &lsB[1][0], bBase, ch0);     // p6 (+4 rd)
    STG(0, 3, t + 2);
    PH_PRE(4); mfmaQ<1,0>(acc, a1, b0); PH_END();

    STG(1, 0, t + 3);                        // p7
    WVMC(2);                                 // tile t+2 fully staged
    PH_PRE(0); mfmaQ<0,1>(acc, a0, b1); PH_END();

    ldA4<0>(a0, &lsA[0][0], aBase, ch0);     // p8 (+12 rd, buf0 t+2 visible)
    ldB2<0>(b0, &lsB[0][0], bBase, ch0);
    STG(1, 1, t + 3);
    PH_PRE(12); mfmaQ<1,1>(acc, a1, b1); PH_END();
  }

  // ---- peeled last pair: tiles 30 (buf0), 31 (buf1); drain exactly
  ldA4<1>(a1, &lsA[0][0], aBase, ch0);
  STG(1, 2, 31);
  PH_PRE(8); mfmaQ<0,0>(acc, a0, b0); PH_END();

  ldB2<1>(b1, &lsB[0][0], bBase, ch0);
  STG(1, 3, 31);
  PH_PRE(4); mfmaQ<1,0>(acc, a1, b0); PH_END();

  WVMC(0);                                   // tile 31 fully staged
  PH_PRE(0); mfmaQ<0,1>(acc, a0, b1); PH_END();

  ldA4<0>(a0, &lsA[1][0], aBase, ch0);
  ldB2<0>(b0, &lsB[1][0], bBase, ch0);
  PH_PRE(12); mfmaQ<1,1>(acc, a1, b1); PH_END();

  ldA4<1>(a1, &lsA[1][0], aBase, ch0);
  PH_PRE(8); mfmaQ<0,0>(acc, a0, b0); PH_END();

  ldB2<1>(b1, &lsB[1][0], bBase, ch0);
  PH_PRE(4); mfmaQ<1,0>(acc, a1, b0); PH_END();

  PH_PRE(0); mfmaQ<0,1>(acc, a0, b1); PH_END();

  PH_PRE(0); mfmaQ<1,1>(acc, a1, b1);
#undef STG

  // ---------------- epilogue: wave covers 64 cols = half of one (head, q/k/v) chunk
  const int col0  = nBase + wn * 64;           // wave-uniform, multiple of 64
  const int chunk = col0 >> 7;
  const int hh = chunk / 3, tq = chunk - 3 * hh;
  const int dbase = col0 & 127;                // 0 or 64 within the head chunk

  if (tq == 2) {                               // V: transposed [B,H,D,S], 4 s per store
#pragma unroll
    for (int nf = 0; nf < 4; nf++) {
      int d = dbase + nf * 16 + lm;
      float bv = bias[col0 + nf * 16 + lm];
#pragma unroll
      for (int mf = 0; mf < 8; mf++) {
        int row0 = mBase + wm * 128 + mf * 16 + quad * 4;
        int b = row0 >> 10, s0 = row0 & 1023;
        unsigned u0 = (unsigned)f2bf(acc[mf][nf][0] + bv) | ((unsigned)f2bf(acc[mf][nf][1] + bv) << 16);
        unsigned u1 = (unsigned)f2bf(acc[mf][nf][2] + bv) | ((unsigned)f2bf(acc[mf][nf][3] + bv) << 16);
        uint2 pk; pk.x = u0; pk.y = u1;
        *(uint2*)(Vt + ((size_t)(b * NUM_HEADS + hh) * HEAD_SIZE + d) * SEQ + s0) = pk;
      }
    }
  } else {
    unsigned short* dst = (tq == 0) ? Qb : Kb;
    if (dbase == 0) {
      // rotary pair: nf=0 (d=lm) with nf=1 (d=16+lm); nf=2,3 passthrough
      const float inv = exp2f(-0.8304820237f * (float)lm);   // 10000^(-lm/16)
      const float bv0 = bias[col0 + lm];
      const float bv1 = bias[col0 + 16 + lm];
#pragma unroll
      for (int mf = 0; mf < 8; mf++) {
        int row0 = mBase + wm * 128 + mf * 16 + quad * 4;
#pragma unroll
        for (int r = 0; r < 4; r++) {
          int row = row0 + r;
          int b = row >> 10, s = row & 1023;
          float pos = (float)pos_ids[row];
          float sn, cs;
          sincosf(pos * inv, &sn, &cs);
          float x1 = acc[mf][0][r] + bv0;
          float x2 = acc[mf][1][r] + bv1;
          size_t rb = ((size_t)(b * NUM_HEADS + hh) * SEQ + s) * HEAD_SIZE;
          dst[rb + lm]      = f2bf(x1 * cs - x2 * sn);
          dst[rb + 16 + lm] = f2bf(x1 * sn + x2 * cs);
        }
      }
#pragma unroll
      for (int nf = 2; nf < 4; nf++) {
        int d = nf * 16 + lm;
        float bv = bias[col0 + d];
#pragma unroll
        for (int mf = 0; mf < 8; mf++) {
          int row0 = mBase + wm * 128 + mf * 16 + quad * 4;
#pragma unroll
          for (int r = 0; r < 4; r++) {
            int row = row0 + r;
            int b = row >> 10, s = row & 1023;
            dst[((size_t)(b * NUM_HEADS + hh) * SEQ + s) * HEAD_SIZE + d] = f2bf(acc[mf][nf][r] + bv);
          }
        }
      }
    } else {
#pragma unroll
      for (int nf = 0; nf < 4; nf++) {
        int d = 64 + nf * 16 + lm;
        float bv = bias[col0 + nf * 16 + lm];
#pragma unroll
        for (int mf = 0; mf < 8; mf++) {
          int row0 = mBase + wm * 128 + mf * 16 + quad * 4;
#pragma unroll
          for (int r = 0; r < 4; r++) {
            int row = row0 + r;
            int b = row >> 10, s = row & 1023;
            dst[((size_t)(b * NUM_HEADS + hh) * SEQ + s) * HEAD_SIZE + d] = f2bf(acc[mf][nf][r] + bv);
          }
        }
      }
    }
  }
}

// ---------------------------------------------------------------- dense GEMM (unchanged: 128x128 dbuf)
__global__ __launch_bounds__(256) void gemm_dense(
    const unsigned short* __restrict__ A,   // [M][K] bf16
    const unsigned short* __restrict__ B,   // [N][K] bf16
    const float* __restrict__ bias,         // [N]
    float* __restrict__ Cf,                 // [M][N] fp32
    int M, int N, int K)
{
  __shared__ unsigned short lsA[2][128*32];
  __shared__ unsigned short lsB[2][128*32];
  const int tid  = threadIdx.x;
  const int w    = tid >> 6, lane = tid & 63;
  const int quad = lane >> 4, lm = lane & 15;
  const int wm   = w & 1, wn = w >> 1;
  const int mBase = blockIdx.y * 128;
  const int nBase = blockIdx.x * 128;
  const int swz = (lm >> 1) & 3;

  const f32x4 zero4 = {0.f, 0.f, 0.f, 0.f};
  f32x4 acc[4][4];
#pragma unroll
  for (int i = 0; i < 4; i++)
#pragma unroll
    for (int j = 0; j < 4; j++) acc[i][j] = zero4;

  const int cg = ((tid & 3) ^ ((tid >> 3) & 3)) * 16;

  auto stage = [&](int bufi, int k0) {
#pragma unroll
    for (int i = 0; i < 2; i++) {
      int off = i * 4096 + tid * 16;
      int row = off >> 6;
      cp16((char*)&lsA[bufi][0] + off, (const char*)(A + (size_t)(mBase + row) * K + k0) + cg);
    }
#pragma unroll
    for (int i = 0; i < 2; i++) {
      int off = i * 4096 + tid * 16;
      int row = off >> 6;
      cp16((char*)&lsB[bufi][0] + off, (const char*)(B + (size_t)(nBase + row) * K + k0) + cg);
    }
  };

  int buf = 0;
  stage(0, 0);

  for (int k0 = 0; k0 < K; k0 += 32) {
    __syncthreads();
    bf16x8 af[4], bfr[4];
#pragma unroll
    for (int mf = 0; mf < 4; mf++)
      af[mf] = *(const bf16x8*)(&lsA[buf][(wm * 64 + mf * 16 + lm) * 32 + (quad ^ swz) * 8]);
#pragma unroll
    for (int nf = 0; nf < 4; nf++)
      bfr[nf] = *(const bf16x8*)(&lsB[buf][(wn * 64 + nf * 16 + lm) * 32 + (quad ^ swz) * 8]);
    if (k0 + 32 < K) stage(buf ^ 1, k0 + 32);
#pragma unroll
    for (int mf = 0; mf < 4; mf++)
#pragma unroll
      for (int nf = 0; nf < 4; nf++)
        acc[mf][nf] = __builtin_amdgcn_mfma_f32_16x16x32_bf16(af[mf], bfr[nf], acc[mf][nf], 0, 0, 0);
    buf ^= 1;
  }

#pragma unroll
  for (int nf = 0; nf < 4; nf++) {
    int col = nBase + wn * 64 + nf * 16 + lm;
    float bv = bias[col];
#pragma unroll
    for (int mf = 0; mf < 4; mf++) {
      int row0 = mBase + wm * 64 + mf * 16 + quad * 4;
#pragma unroll
      for (int r = 0; r < 4; r++)
        Cf[(size_t)(row0 + r) * N + col] = acc[mf][nf][r] + bv;
    }
  }
}

// ---------------------------------------------------------------- flash attention (UNCHANGED)
__global__ __launch_bounds__(256, 2) void flash_attn_k(
    const unsigned short* __restrict__ Q,
    const unsigned short* __restrict__ K,
    const unsigned short* __restrict__ VT,   // [B,H,D,S]
    unsigned short* __restrict__ O)          // [TOTAL][HIDDEN] bf16
{
  const int bh = blockIdx.x;
  const int pair = blockIdx.y;
  const int qa = 15 - pair, qb = pair;
  const int b = bh >> 4, h = bh & 15;
  const size_t base = (size_t)bh * SEQ * HEAD_SIZE;
  const unsigned short* Qp = Q + base;
  const unsigned short* Kp = K + base;
  const unsigned short* Vp = VT + base;      // [d][s]

  __shared__ unsigned short Ks[2][4][64*32]; // 2 x 16 KB
  __shared__ unsigned short Vl[2][128*64];   // 2 x 16 KB
  __shared__ unsigned short Ps[64][72];      // 9 KB

  const int tid  = threadIdx.x;
  const int w    = tid >> 6, lane = tid & 63;
  const int quad = lane >> 4, lm = lane & 15;
  const int swz4 = (lm >> 1) & 3;
  const int swz8 = lm & 7;
  const int cgK = ((tid & 3) ^ ((tid >> 3) & 3)) * 8;
  const int cgV = ((tid & 7) ^ ((tid >> 3) & 7)) * 8;

  const float K1 = 0.1275156876f;            // (1/sqrt(128)) * log2(e)
  const f32x4 zero4 = {0.f, 0.f, 0.f, 0.f};
  const __bf16 one = (__bf16)1.0f;
  const bf16x8 vones = {one, one, one, one, one, one, one, one};

  auto stage = [&](int buf, int kt) {
    const unsigned short* krow = Kp + (size_t)(kt * 64 + (tid >> 2)) * HEAD_SIZE + cgK;
#pragma unroll
    for (int kk = 0; kk < 4; kk++)
      cp16((char*)&Ks[buf][kk][0] + tid * 16, krow + kk * 32);
#pragma unroll
    for (int i = 0; i < 4; i++) {
      int off = i * 4096 + tid * 16;
      int d = off >> 7;
      cp16((char*)&Vl[buf][0] + off, Vp + (size_t)d * SEQ + kt * 64 + cgV);
    }
  };

  int buf = 0;
  stage(0, 0);

  for (int ph = 0; ph < 2; ph++) {
    const int qt = ph ? qb : qa;
    bf16x8 qf[4];
    {
      const unsigned short* qrow = Qp + (size_t)(qt * 64 + w * 16 + lm) * HEAD_SIZE;
#pragma unroll
      for (int kk = 0; kk < 4; kk++)
        qf[kk] = *(const bf16x8*)(qrow + kk * 32 + quad * 8);
    }
    float m_r[4];
#pragma unroll
    for (int r = 0; r < 4; r++) m_r[r] = -1e30f;
    f32x4 lacc = zero4;
    f32x4 o[8];
#pragma unroll
    for (int i = 0; i < 8; i++) o[i] = zero4;

    for (int kt = 0; kt <= qt; ++kt) {
      __syncthreads();
      bool last = (ph == 1) && (kt == qt);
      if (!last) stage(buf ^ 1, (kt < qt) ? kt + 1 : 0);

      f32x4 sf[4];
#pragma unroll
      for (int nf = 0; nf < 4; nf++) {
        f32x4 accs = zero4;
#pragma unroll
        for (int kk = 0; kk < 4; kk++) {
          bf16x8 kfrag = *(const bf16x8*)(&Ks[buf][kk][(nf * 16 + lm) * 32 + (quad ^ swz4) * 8]);
          accs = __builtin_amdgcn_mfma_f32_16x16x32_bf16(qf[kk], kfrag, accs, 0, 0, 0);
        }
        sf[nf] = accs;
      }
      if (kt == qt) {
        int qrow0 = qt * 64 + w * 16 + quad * 4;
#pragma unroll
        for (int nf = 0; nf < 4; nf++) {
          int col = kt * 64 + nf * 16 + lm;
#pragma unroll
          for (int r = 0; r < 4; r++)
            if (col > qrow0 + r) sf[nf][r] = -1e30f;
        }
      }
      float alpha[4];
#pragma unroll
      for (int r = 0; r < 4; r++) {
        float v = fmaxf(fmaxf(sf[0][r], sf[1][r]), fmaxf(sf[2][r], sf[3][r]));
        v = fmaxf(v, __shfl_xor(v, 1));
        v = fmaxf(v, __shfl_xor(v, 2));
        v = fmaxf(v, __shfl_xor(v, 4));
        v = fmaxf(v, __shfl_xor(v, 8));
        float mn = fmaxf(m_r[r], v);
        alpha[r] = exp2f((m_r[r] - mn) * K1);
        m_r[r] = mn;
      }
#pragma unroll
      for (int nf = 0; nf < 4; nf++)
#pragma unroll
        for (int r = 0; r < 4; r++) {
          float p = exp2f((sf[nf][r] - m_r[r]) * K1);
          Ps[w * 16 + quad * 4 + r][nf * 16 + lm] = f2bf(p);
        }
#pragma unroll
      for (int df = 0; df < 8; df++)
#pragma unroll
        for (int r = 0; r < 4; r++) o[df][r] *= alpha[r];
#pragma unroll
      for (int r = 0; r < 4; r++) lacc[r] *= alpha[r];

#pragma unroll
      for (int ks = 0; ks < 2; ks++) {
        bf16x8 pf = *(const bf16x8*)(&Ps[w * 16 + lm][ks * 32 + quad * 8]);
        lacc = __builtin_amdgcn_mfma_f32_16x16x32_bf16(pf, vones, lacc, 0, 0, 0);
#pragma unroll
        for (int df = 0; df < 8; df++) {
          bf16x8 vf = *(const bf16x8*)(&Vl[buf][(df * 16 + lm) * 64 + (((ks * 4 + quad) ^ swz8)) * 8]);
          o[df] = __builtin_amdgcn_mfma_f32_16x16x32_bf16(pf, vf, o[df], 0, 0, 0);
        }
      }
      buf ^= 1;
    }

    float rl[4];
#pragma unroll
    for (int r = 0; r < 4; r++) rl[r] = 1.f / lacc[r];
    int row0 = b * SEQ + qt * 64 + w * 16 + quad * 4;
#pragma unroll
    for (int df = 0; df < 8; df++) {
      int col = h * HEAD_SIZE + df * 16 + lm;
#pragma unroll
      for (int r = 0; r < 4; r++)
        O[(size_t)(row0 + r) * HIDDEN + col] = f2bf(o[df][r] * rl[r]);
    }
  }
}

// ---------------------------------------------------------------- launch
extern "C" void kernel_launch(void* const* d_in, const int* in_sizes, int n_in,
                              void* d_out, int out_size, void* d_ws, size_t ws_size,
                              hipStream_t stream)
{
  const float* hs   = (const float*)d_in[0];
  const float* wqkv = (const float*)d_in[2];
  const float* bqkv = (const float*)d_in[3];
  const float* wd   = (const float*)d_in[4];
  const float* bd   = (const float*)d_in[5];
  const int*   pos  = (const int*)d_in[6];

  char* ws = (char*)d_ws;
  unsigned short* hsb = (unsigned short*)ws;  ws += (size_t)TOTAL * HIDDEN * 2;   // 16.8 MB
  unsigned short* wqb = (unsigned short*)ws;  ws += (size_t)QKV_N * HIDDEN * 2;   // 25.2 MB
  unsigned short* wdb = (unsigned short*)ws;  ws += (size_t)HIDDEN * HIDDEN * 2;  //  8.4 MB
  unsigned short* Qb  = (unsigned short*)ws;  ws += (size_t)TOTAL * HIDDEN * 2;
  unsigned short* Kb  = (unsigned short*)ws;  ws += (size_t)TOTAL * HIDDEN * 2;
  unsigned short* Vt  = (unsigned short*)ws;  ws += (size_t)TOTAL * HIDDEN * 2;   // [B,H,D,S]
  unsigned short* attnb = hsb;               // hsb dead after QKV GEMM
  if (ws_size < (size_t)(ws - (char*)d_ws)) return;  // ~100.8 MB needed

  const int na = TOTAL * HIDDEN, nb = QKV_N * HIDDEN, nc = HIDDEN * HIDDEN;
  f32_to_bf16_multi<<<(na + nb + nc) / 1024, 256, 0, stream>>>(
      hs, hsb, na, wqkv, wqb, nb, wd, wdb, nc);

  gemm_qkv_8ph<<<dim3(384), 512, 0, stream>>>(hsb, wqb, bqkv, pos, Qb, Kb, Vt);

  flash_attn_k<<<dim3(64, 8), 256, 0, stream>>>(Qb, Kb, Vt, attnb);

  gemm_dense<<<dim3(HIDDEN / 128, TOTAL / 128), 256, 0, stream>>>(
      attnb, wdb, bd, (float*)d_out, TOTAL, HIDDEN, HIDDEN);
}

// Round 3
// 379.949 us; speedup vs baseline: 1.1206x; 1.1206x over previous
//
#include <hip/hip_runtime.h>
#include <stdint.h>

#define NUM_HEADS 16
#define HIDDEN    2048
#define HEAD_SIZE 128
#define TOTAL     4096
#define SEQ       1024
#define QKV_N     (3*HIDDEN)   // 6144

typedef __bf16 bf16x8 __attribute__((ext_vector_type(8)));
typedef float  f32x4  __attribute__((ext_vector_type(4)));

__device__ __forceinline__ unsigned short f2bf(float f) {
  unsigned u = __float_as_uint(f);
  u += 0x7FFFu + ((u >> 16) & 1u);          // RNE
  return (unsigned short)(u >> 16);
}
__device__ __forceinline__ float bf2f(unsigned short h) {
  return __uint_as_float(((unsigned)h) << 16);
}
// async global->LDS, 16B per lane. LDS dest must be wave-uniform base + lane*16.
__device__ __forceinline__ void cp16(void* lds, const void* g) {
  __builtin_amdgcn_global_load_lds(
      (const __attribute__((address_space(1))) void*)g,
      (__attribute__((address_space(3))) void*)lds, 16, 0, 0);
}

#define WVMC(n)  asm volatile("s_waitcnt vmcnt(" #n ")" ::: "memory")
#define RBAR()   asm volatile("s_barrier" ::: "memory")

// ---------------------------------------------------------------- fused convert (3 tensors)
__global__ __launch_bounds__(256) void f32_to_bf16_multi(
    const float* __restrict__ a, unsigned short* __restrict__ oa, int na,
    const float* __restrict__ b, unsigned short* __restrict__ ob, int nb,
    const float* __restrict__ c, unsigned short* __restrict__ oc, int nc)
{
  int i = (blockIdx.x * 256 + threadIdx.x) * 4;
  const float* src; unsigned short* dst;
  if (i < na)            { src = a; dst = oa; }
  else if (i < na + nb)  { i -= na; src = b; dst = ob; }
  else                   { i -= na + nb; if (i >= nc) return; src = c; dst = oc; }
  float4 v = *(const float4*)(src + i);
  unsigned p0 = (unsigned)f2bf(v.x) | ((unsigned)f2bf(v.y) << 16);
  unsigned p1 = (unsigned)f2bf(v.z) | ((unsigned)f2bf(v.w) << 16);
  uint2 pk; pk.x = p0; pk.y = p1;
  *(uint2*)(dst + i) = pk;
}

// ---------------------------------------------------------------- QKV GEMM, FAT WAVES (r0)
// + R3 change: 3-buffer LDS rotation with COUNTED vmcnt(6) and raw s_barrier,
//   replacing __syncthreads()'s structural vmcnt(0) drain (the ~20% stall).
// Ledger: S_j (6 loads staging tile j) issued at iter j-2. Entering iter k:
//   outstanding <= S_k u S_{k+1} (12). WVMC(6) -> S_k complete (in-order) ->
//   barrier -> reads of buf k%3 safe. stage S_{k+2} into buf (k-1)%3 whose
//   reads retired before this barrier (WAR safe). Last 2 iters: WVMC(0).
__global__ __launch_bounds__(256, 2) void gemm_qkv(
    const unsigned short* __restrict__ A,   // [M][K] bf16
    const unsigned short* __restrict__ B,   // [N][K] bf16
    const float* __restrict__ bias,         // [N]
    const int* __restrict__ pos_ids,        // [TOTAL]
    unsigned short* __restrict__ Qb,
    unsigned short* __restrict__ Kb,
    unsigned short* __restrict__ Vt,
    int M, int N, int K)
{
  __shared__ unsigned short lsA[3][128*32]; // 3 x 8 KB, row pitch 64B
  __shared__ unsigned short lsB[3][256*32]; // 3 x 16 KB
  const int tid  = threadIdx.x;
  const int w    = tid >> 6, lane = tid & 63;
  const int quad = lane >> 4, lm = lane & 15;
  const int wm   = w >> 1, wn = w & 1;      // row-half (64), col-half (128)
  const int mBase = blockIdx.y * 128;
  const int nBase = blockIdx.x * 256;
  const int swz = (lm >> 1) & 3;            // read-side chunk swizzle (row>>1)&3

  const f32x4 zero4 = {0.f, 0.f, 0.f, 0.f};
  f32x4 acc[4][8];
#pragma unroll
  for (int i = 0; i < 4; i++)
#pragma unroll
    for (int j = 0; j < 8; j++) acc[i][j] = zero4;

  const int cg = ((tid & 3) ^ ((tid >> 3) & 3)) * 16;  // swizzled global 16B chunk

  auto stage = [&](int bufi, int k0) {
#pragma unroll
    for (int i = 0; i < 2; i++) {           // A: 128 rows x 64B
      int off = i * 4096 + tid * 16;
      int row = off >> 6;
      cp16((char*)&lsA[bufi][0] + off, (const char*)(A + (size_t)(mBase + row) * K + k0) + cg);
    }
#pragma unroll
    for (int i = 0; i < 4; i++) {           // B: 256 rows x 64B
      int off = i * 4096 + tid * 16;
      int row = off >> 6;
      cp16((char*)&lsB[bufi][0] + off, (const char*)(B + (size_t)(nBase + row) * K + k0) + cg);
    }
  };

  stage(0, 0);                               // S_0
  stage(1, 32);                              // S_1

  int br = 0;                                // read buffer = tile index % 3
#pragma unroll 1
  for (int k0 = 0; k0 < K; k0 += 32) {
    if (k0 + 64 < K) { WVMC(6); } else { WVMC(0); }
    RBAR();                                  // buf br fully staged, WAR retired
    bf16x8 af[4], bfr[8];
#pragma unroll
    for (int mf = 0; mf < 4; mf++)
      af[mf] = *(const bf16x8*)(&lsA[br][(wm * 64 + mf * 16 + lm) * 32 + (quad ^ swz) * 8]);
#pragma unroll
    for (int nf = 0; nf < 8; nf++)
      bfr[nf] = *(const bf16x8*)(&lsB[br][(wn * 128 + nf * 16 + lm) * 32 + (quad ^ swz) * 8]);
    if (k0 + 64 < K) stage(br == 0 ? 2 : br - 1, k0 + 64);   // S_{k+2} -> buf (k-1)%3
#pragma unroll
    for (int mf = 0; mf < 4; mf++)
#pragma unroll
      for (int nf = 0; nf < 8; nf++)
        acc[mf][nf] = __builtin_amdgcn_mfma_f32_16x16x32_bf16(af[mf], bfr[nf], acc[mf][nf], 0, 0, 0);
    br = (br == 2) ? 0 : br + 1;
  }

  // epilogue: C layout col=lane&15, row=quad*4+r. Wave's 128 cols = one (head, q/k/v) chunk.
  const int col0 = nBase + wn * 128;         // wave-uniform, multiple of 128
  const int chunk = col0 >> 7;
  const int hh = chunk / 3, t = chunk - 3 * hh;
  if (t == 2) {                              // V: write transposed [B,H,D,S], 4 s packed / store
#pragma unroll
    for (int nf = 0; nf < 8; nf++) {
      int d = nf * 16 + lm;
      float bv = bias[col0 + d];
#pragma unroll
      for (int mf = 0; mf < 4; mf++) {
        int row0 = mBase + wm * 64 + mf * 16 + quad * 4;
        int b = row0 >> 10, s0 = row0 & 1023;
        unsigned u0 = (unsigned)f2bf(acc[mf][nf][0] + bv) | ((unsigned)f2bf(acc[mf][nf][1] + bv) << 16);
        unsigned u1 = (unsigned)f2bf(acc[mf][nf][2] + bv) | ((unsigned)f2bf(acc[mf][nf][3] + bv) << 16);
        uint2 pk; pk.x = u0; pk.y = u1;
        *(uint2*)(Vt + ((size_t)(b * NUM_HEADS + hh) * HEAD_SIZE + d) * SEQ + s0) = pk;
      }
    }
  } else {
    unsigned short* dst = (t == 0) ? Qb : Kb;
    // nf=0 (d=lm) pairs with nf=1 (d=lm+16): fused NeoX rotary.
    {
      const float inv = exp2f(-0.8304820237f * (float)lm);   // 10000^(-lm/16)
      const float bv0 = bias[col0 + lm];
      const float bv1 = bias[col0 + 16 + lm];
#pragma unroll
      for (int mf = 0; mf < 4; mf++) {
        int row0 = mBase + wm * 64 + mf * 16 + quad * 4;
#pragma unroll
        for (int r = 0; r < 4; r++) {
          int row = row0 + r;
          int b = row >> 10, s = row & 1023;
          float pos = (float)pos_ids[row];
          float sn, cs;
          sincosf(pos * inv, &sn, &cs);
          float x1 = acc[mf][0][r] + bv0;
          float x2 = acc[mf][1][r] + bv1;
          size_t rb = ((size_t)(b * NUM_HEADS + hh) * SEQ + s) * HEAD_SIZE;
          dst[rb + lm]      = f2bf(x1 * cs - x2 * sn);
          dst[rb + 16 + lm] = f2bf(x1 * sn + x2 * cs);
        }
      }
    }
#pragma unroll
    for (int nf = 2; nf < 8; nf++) {
      int d = nf * 16 + lm;
      float bv = bias[col0 + d];
#pragma unroll
      for (int mf = 0; mf < 4; mf++) {
        int row0 = mBase + wm * 64 + mf * 16 + quad * 4;
#pragma unroll
        for (int r = 0; r < 4; r++) {
          int row = row0 + r;
          int b = row >> 10, s = row & 1023;
          dst[((size_t)(b * NUM_HEADS + hh) * SEQ + s) * HEAD_SIZE + d] = f2bf(acc[mf][nf][r] + bv);
        }
      }
    }
  }
}

// ---------------------------------------------------------------- dense GEMM (r0: 128x128 dbuf)
__global__ __launch_bounds__(256) void gemm_dense(
    const unsigned short* __restrict__ A,   // [M][K] bf16
    const unsigned short* __restrict__ B,   // [N][K] bf16
    const float* __restrict__ bias,         // [N]
    float* __restrict__ Cf,                 // [M][N] fp32
    int M, int N, int K)
{
  __shared__ unsigned short lsA[2][128*32];
  __shared__ unsigned short lsB[2][128*32];
  const int tid  = threadIdx.x;
  const int w    = tid >> 6, lane = tid & 63;
  const int quad = lane >> 4, lm = lane & 15;
  const int wm   = w & 1, wn = w >> 1;
  const int mBase = blockIdx.y * 128;
  const int nBase = blockIdx.x * 128;
  const int swz = (lm >> 1) & 3;

  const f32x4 zero4 = {0.f, 0.f, 0.f, 0.f};
  f32x4 acc[4][4];
#pragma unroll
  for (int i = 0; i < 4; i++)
#pragma unroll
    for (int j = 0; j < 4; j++) acc[i][j] = zero4;

  const int cg = ((tid & 3) ^ ((tid >> 3) & 3)) * 16;

  auto stage = [&](int bufi, int k0) {
#pragma unroll
    for (int i = 0; i < 2; i++) {
      int off = i * 4096 + tid * 16;
      int row = off >> 6;
      cp16((char*)&lsA[bufi][0] + off, (const char*)(A + (size_t)(mBase + row) * K + k0) + cg);
    }
#pragma unroll
    for (int i = 0; i < 2; i++) {
      int off = i * 4096 + tid * 16;
      int row = off >> 6;
      cp16((char*)&lsB[bufi][0] + off, (const char*)(B + (size_t)(nBase + row) * K + k0) + cg);
    }
  };

  int buf = 0;
  stage(0, 0);

  for (int k0 = 0; k0 < K; k0 += 32) {
    __syncthreads();
    bf16x8 af[4], bfr[4];
#pragma unroll
    for (int mf = 0; mf < 4; mf++)
      af[mf] = *(const bf16x8*)(&lsA[buf][(wm * 64 + mf * 16 + lm) * 32 + (quad ^ swz) * 8]);
#pragma unroll
    for (int nf = 0; nf < 4; nf++)
      bfr[nf] = *(const bf16x8*)(&lsB[buf][(wn * 64 + nf * 16 + lm) * 32 + (quad ^ swz) * 8]);
    if (k0 + 32 < K) stage(buf ^ 1, k0 + 32);
#pragma unroll
    for (int mf = 0; mf < 4; mf++)
#pragma unroll
      for (int nf = 0; nf < 4; nf++)
        acc[mf][nf] = __builtin_amdgcn_mfma_f32_16x16x32_bf16(af[mf], bfr[nf], acc[mf][nf], 0, 0, 0);
    buf ^= 1;
  }

#pragma unroll
  for (int nf = 0; nf < 4; nf++) {
    int col = nBase + wn * 64 + nf * 16 + lm;
    float bv = bias[col];
#pragma unroll
    for (int mf = 0; mf < 4; mf++) {
      int row0 = mBase + wm * 64 + mf * 16 + quad * 4;
#pragma unroll
      for (int r = 0; r < 4; r++)
        Cf[(size_t)(row0 + r) * N + col] = acc[mf][nf][r] + bv;
    }
  }
}

// ---------------------------------------------------------------- flash attention (r0 UNCHANGED)
__global__ __launch_bounds__(256, 2) void flash_attn_k(
    const unsigned short* __restrict__ Q,
    const unsigned short* __restrict__ K,
    const unsigned short* __restrict__ VT,   // [B,H,D,S]
    unsigned short* __restrict__ O)          // [TOTAL][HIDDEN] bf16
{
  const int bh = blockIdx.x;
  const int pair = blockIdx.y;
  const int qa = 15 - pair, qb = pair;
  const int b = bh >> 4, h = bh & 15;
  const size_t base = (size_t)bh * SEQ * HEAD_SIZE;
  const unsigned short* Qp = Q + base;
  const unsigned short* Kp = K + base;
  const unsigned short* Vp = VT + base;      // [d][s]

  __shared__ unsigned short Ks[2][4][64*32]; // 2 x 16 KB
  __shared__ unsigned short Vl[2][128*64];   // 2 x 16 KB
  __shared__ unsigned short Ps[64][72];      // 9 KB

  const int tid  = threadIdx.x;
  const int w    = tid >> 6, lane = tid & 63;
  const int quad = lane >> 4, lm = lane & 15;
  const int swz4 = (lm >> 1) & 3;
  const int swz8 = lm & 7;
  const int cgK = ((tid & 3) ^ ((tid >> 3) & 3)) * 8;
  const int cgV = ((tid & 7) ^ ((tid >> 3) & 7)) * 8;

  const float K1 = 0.1275156876f;            // (1/sqrt(128)) * log2(e)
  const f32x4 zero4 = {0.f, 0.f, 0.f, 0.f};
  const __bf16 one = (__bf16)1.0f;
  const bf16x8 vones = {one, one, one, one, one, one, one, one};

  auto stage = [&](int buf, int kt) {
    const unsigned short* krow = Kp + (size_t)(kt * 64 + (tid >> 2)) * HEAD_SIZE + cgK;
#pragma unroll
    for (int kk = 0; kk < 4; kk++)
      cp16((char*)&Ks[buf][kk][0] + tid * 16, krow + kk * 32);
#pragma unroll
    for (int i = 0; i < 4; i++) {
      int off = i * 4096 + tid * 16;
      int d = off >> 7;
      cp16((char*)&Vl[buf][0] + off, Vp + (size_t)d * SEQ + kt * 64 + cgV);
    }
  };

  int buf = 0;
  stage(0, 0);

  for (int ph = 0; ph < 2; ph++) {
    const int qt = ph ? qb : qa;
    bf16x8 qf[4];
    {
      const unsigned short* qrow = Qp + (size_t)(qt * 64 + w * 16 + lm) * HEAD_SIZE;
#pragma unroll
      for (int kk = 0; kk < 4; kk++)
        qf[kk] = *(const bf16x8*)(qrow + kk * 32 + quad * 8);
    }
    float m_r[4];
#pragma unroll
    for (int r = 0; r < 4; r++) m_r[r] = -1e30f;
    f32x4 lacc = zero4;
    f32x4 o[8];
#pragma unroll
    for (int i = 0; i < 8; i++) o[i] = zero4;

    for (int kt = 0; kt <= qt; ++kt) {
      __syncthreads();
      bool last = (ph == 1) && (kt == qt);
      if (!last) stage(buf ^ 1, (kt < qt) ? kt + 1 : 0);

      f32x4 sf[4];
#pragma unroll
      for (int nf = 0; nf < 4; nf++) {
        f32x4 accs = zero4;
#pragma unroll
        for (int kk = 0; kk < 4; kk++) {
          bf16x8 kfrag = *(const bf16x8*)(&Ks[buf][kk][(nf * 16 + lm) * 32 + (quad ^ swz4) * 8]);
          accs = __builtin_amdgcn_mfma_f32_16x16x32_bf16(qf[kk], kfrag, accs, 0, 0, 0);
        }
        sf[nf] = accs;
      }
      if (kt == qt) {
        int qrow0 = qt * 64 + w * 16 + quad * 4;
#pragma unroll
        for (int nf = 0; nf < 4; nf++) {
          int col = kt * 64 + nf * 16 + lm;
#pragma unroll
          for (int r = 0; r < 4; r++)
            if (col > qrow0 + r) sf[nf][r] = -1e30f;
        }
      }
      float alpha[4];
#pragma unroll
      for (int r = 0; r < 4; r++) {
        float v = fmaxf(fmaxf(sf[0][r], sf[1][r]), fmaxf(sf[2][r], sf[3][r]));
        v = fmaxf(v, __shfl_xor(v, 1));
        v = fmaxf(v, __shfl_xor(v, 2));
        v = fmaxf(v, __shfl_xor(v, 4));
        v = fmaxf(v, __shfl_xor(v, 8));
        float mn = fmaxf(m_r[r], v);
        alpha[r] = exp2f((m_r[r] - mn) * K1);
        m_r[r] = mn;
      }
#pragma unroll
      for (int nf = 0; nf < 4; nf++)
#pragma unroll
        for (int r = 0; r < 4; r++) {
          float p = exp2f((sf[nf][r] - m_r[r]) * K1);
          Ps[w * 16 + quad * 4 + r][nf * 16 + lm] = f2bf(p);
        }
#pragma unroll
      for (int df = 0; df < 8; df++)
#pragma unroll
        for (int r = 0; r < 4; r++) o[df][r] *= alpha[r];
#pragma unroll
      for (int r = 0; r < 4; r++) lacc[r] *= alpha[r];

#pragma unroll
      for (int ks = 0; ks < 2; ks++) {
        bf16x8 pf = *(const bf16x8*)(&Ps[w * 16 + lm][ks * 32 + quad * 8]);
        lacc = __builtin_amdgcn_mfma_f32_16x16x32_bf16(pf, vones, lacc, 0, 0, 0);
#pragma unroll
        for (int df = 0; df < 8; df++) {
          bf16x8 vf = *(const bf16x8*)(&Vl[buf][(df * 16 + lm) * 64 + (((ks * 4 + quad) ^ swz8)) * 8]);
          o[df] = __builtin_amdgcn_mfma_f32_16x16x32_bf16(pf, vf, o[df], 0, 0, 0);
        }
      }
      buf ^= 1;
    }

    float rl[4];
#pragma unroll
    for (int r = 0; r < 4; r++) rl[r] = 1.f / lacc[r];
    int row0 = b * SEQ + qt * 64 + w * 16 + quad * 4;
#pragma unroll
    for (int df = 0; df < 8; df++) {
      int col = h * HEAD_SIZE + df * 16 + lm;
#pragma unroll
      for (int r = 0; r < 4; r++)
        O[(size_t)(row0 + r) * HIDDEN + col] = f2bf(o[df][r] * rl[r]);
    }
  }
}

// ---------------------------------------------------------------- launch
extern "C" void kernel_launch(void* const* d_in, const int* in_sizes, int n_in,
                              void* d_out, int out_size, void* d_ws, size_t ws_size,
                              hipStream_t stream)
{
  const float* hs   = (const float*)d_in[0];
  const float* wqkv = (const float*)d_in[2];
  const float* bqkv = (const float*)d_in[3];
  const float* wd   = (const float*)d_in[4];
  const float* bd   = (const float*)d_in[5];
  const int*   pos  = (const int*)d_in[6];

  char* ws = (char*)d_ws;
  unsigned short* hsb = (unsigned short*)ws;  ws += (size_t)TOTAL * HIDDEN * 2;   // 16.8 MB
  unsigned short* wqb = (unsigned short*)ws;  ws += (size_t)QKV_N * HIDDEN * 2;   // 25.2 MB
  unsigned short* wdb = (unsigned short*)ws;  ws += (size_t)HIDDEN * HIDDEN * 2;  //  8.4 MB
  unsigned short* Qb  = (unsigned short*)ws;  ws += (size_t)TOTAL * HIDDEN * 2;
  unsigned short* Kb  = (unsigned short*)ws;  ws += (size_t)TOTAL * HIDDEN * 2;
  unsigned short* Vt  = (unsigned short*)ws;  ws += (size_t)TOTAL * HIDDEN * 2;   // [B,H,D,S]
  unsigned short* attnb = hsb;               // hsb dead after QKV GEMM
  if (ws_size < (size_t)(ws - (char*)d_ws)) return;  // ~100.8 MB needed

  const int na = TOTAL * HIDDEN, nb = QKV_N * HIDDEN, nc = HIDDEN * HIDDEN;
  f32_to_bf16_multi<<<(na + nb + nc) / 1024, 256, 0, stream>>>(
      hs, hsb, na, wqkv, wqb, nb, wd, wdb, nc);

  gemm_qkv<<<dim3(QKV_N / 256, TOTAL / 128), 256, 0, stream>>>(
      hsb, wqb, bqkv, pos, Qb, Kb, Vt, TOTAL, QKV_N, HIDDEN);

  flash_attn_k<<<dim3(64, 8), 256, 0, stream>>>(Qb, Kb, Vt, attnb);

  gemm_dense<<<dim3(HIDDEN / 128, TOTAL / 128), 256, 0, stream>>>(
      attnb, wdb, bd, (float*)d_out, TOTAL, HIDDEN, HIDDEN);
}